// Round 11
// baseline (166.641 us; speedup 1.0000x reference)
//
#include <hip/hip_runtime.h>

#define B_    8
#define D_IN  256
#define D_HID 1024
#define D_OUT 40000       // = 200*200
#define HW4   10000       // D_OUT/4
#define CHW4  2560000     // 256*200*200/4

typedef float f32x4 __attribute__((ext_vector_type(4)));

// Kernel 1: hT[k*8+b] = leakyrelu(loc[b,:] @ W1[:,k] + b1[k])
__global__ void mlp1_kernel(const float* __restrict__ loc,
                            const float* __restrict__ W1,
                            const float* __restrict__ b1,
                            float* __restrict__ hT) {
    __shared__ float red[256];
    int g    = blockIdx.x;
    int b    = g >> 4;
    int k0   = (g & 15) * 64;
    int w    = threadIdx.x >> 6;
    int lane = threadIdx.x & 63;
    int k    = k0 + lane;

    float acc = 0.0f;
    #pragma unroll 8
    for (int ii = 0; ii < 64; ++ii) {
        int i = w * 64 + ii;
        acc += loc[b * D_IN + i] * W1[i * D_HID + k];
    }
    red[threadIdx.x] = acc;
    __syncthreads();
    if (w == 0) {
        float s = red[lane] + red[64 + lane] + red[128 + lane] + red[192 + lane];
        s += b1[k];
        s = (s >= 0.0f) ? s : 0.1f * s;
        hT[k * B_ + b] = s;
    }
}

// Kernel 2: split-K partial, float4 over columns, 1-wave blocks, grid (157,KS).
template<int KS>
__global__ void mlp2_partial_kernel(const float* __restrict__ hT,
                                    const float* __restrict__ W2,
                                    float* __restrict__ partial) {
    constexpr int CHUNK = D_HID / KS;
    int j4 = blockIdx.x * 64 + threadIdx.x;
    if (j4 >= HW4) return;
    int ks = blockIdx.y;
    int k0 = ks * CHUNK;
    const f32x4* __restrict__ W24 = (const f32x4*)W2;
    f32x4 acc[B_];
    #pragma unroll
    for (int b = 0; b < B_; ++b) acc[b] = (f32x4)0.0f;
    #pragma unroll 8
    for (int kk = 0; kk < CHUNK; ++kk) {
        int k = k0 + kk;
        f32x4 wv = __builtin_nontemporal_load(&W24[k * HW4 + j4]); // read-once stream
        const float* __restrict__ h = &hT[k * B_];                 // wave-uniform, L2-hit
        #pragma unroll
        for (int b = 0; b < B_; ++b)
            acc[b] += wv * h[b];
    }
    f32x4* __restrict__ p4 = (f32x4*)partial;
    #pragma unroll
    for (int b = 0; b < B_; ++b)
        __builtin_nontemporal_store(acc[b], &p4[(ks * B_ + b) * HW4 + j4]);
}

// Kernel 3: out = x * (1 + b2 + sum_ks partial)  — reduce fused, wv hoisted.
// Grid (625, 8): per-batch stride 160000 vec4 = 16*HW4 -> p invariant per thread.
// Cached (non-nt) out stores: wv is hoisted so L2 pollution is harmless, and
// fill kernels prove cached stores sustain 6.6-7.0 TB/s.
template<int KS>
__global__ void scale_kernel(const float* __restrict__ x,
                             const float* __restrict__ partial,
                             const float* __restrict__ b2,
                             float* __restrict__ out) {
    const int b = blockIdx.y;
    const int g = blockIdx.x * 256 + threadIdx.x;        // 0..159999
    const unsigned p = (unsigned)g % HW4;                // invariant across iters

    const f32x4* __restrict__ p4 = (const f32x4*)partial;
    f32x4 wv = ((const f32x4*)b2)[p] + 1.0f;
    #pragma unroll
    for (int ks = 0; ks < KS; ++ks)
        wv += p4[(ks * B_ + b) * HW4 + p];               // hoisted: once per thread

    const f32x4* __restrict__ x4 = (const f32x4*)x + (size_t)b * CHW4;
    f32x4* __restrict__ o4       = (f32x4*)out + (size_t)b * CHW4;
    #pragma unroll 4
    for (int n = 0; n < 16; ++n) {
        int i = g + n * 160000;
        f32x4 xv = __builtin_nontemporal_load(&x4[i]);   // read-once stream
        o4[i] = xv * wv;                                 // cached write-back
    }
}

template<int KS>
static void launch_rest(const float* x, const float* hT, const float* W2,
                        const float* b2, float* partial, float* out,
                        hipStream_t stream) {
    dim3 g2(157, KS);
    mlp2_partial_kernel<KS><<<g2, 64, 0, stream>>>(hT, W2, partial);
    scale_kernel<KS><<<dim3(625, 8), 256, 0, stream>>>(x, partial, b2, out);
}

extern "C" void kernel_launch(void* const* d_in, const int* in_sizes, int n_in,
                              void* d_out, int out_size, void* d_ws, size_t ws_size,
                              hipStream_t stream) {
    const float* x   = (const float*)d_in[0];
    const float* loc = (const float*)d_in[1];
    const float* W1  = (const float*)d_in[2];
    const float* b1  = (const float*)d_in[3];
    const float* W2  = (const float*)d_in[4];
    const float* b2  = (const float*)d_in[5];
    float* out = (float*)d_out;

    float* hT      = (float*)d_ws;                       // 32 KB
    float* partial = (float*)((char*)d_ws + 32768);

    size_t base = 32768;
    int KS = 1;
    for (int cand = 8; cand >= 1; cand >>= 1) {
        size_t need = base + (size_t)cand * B_ * D_OUT * sizeof(float);
        if (need <= ws_size) { KS = cand; break; }
    }

    mlp1_kernel<<<128, 256, 0, stream>>>(loc, W1, b1, hT);

    switch (KS) {
        case 8:  launch_rest<8>(x, hT, W2, b2, partial, out, stream); break;
        case 4:  launch_rest<4>(x, hT, W2, b2, partial, out, stream); break;
        case 2:  launch_rest<2>(x, hT, W2, b2, partial, out, stream); break;
        default: launch_rest<1>(x, hT, W2, b2, partial, out, stream); break;
    }
}